// Round 2
// baseline (2121.602 us; speedup 1.0000x reference)
//
#include <hip/hip_runtime.h>

#define I_SZ 256
#define H_SZ 512
#define O_SZ 256
#define B_SZ 4096
#define S_SZ 50
#define T_SZ 20
#define G4H  2048
#define BH   ((size_t)B_SZ * H_SZ)
#define CH   10
#define XP_SLICE ((size_t)B_SZ * G4H)   // halves per timestep (frag-ordered)

#define PAD 72

typedef _Float16 half8 __attribute__((ext_vector_type(8)));
typedef _Float16 half4 __attribute__((ext_vector_type(4)));
typedef float f32x4 __attribute__((ext_vector_type(4)));

__device__ __forceinline__ float sigm(float x) {
    return 1.0f / (1.0f + __expf(-x));
}
__device__ __forceinline__ float tanh_fast(float x) {
    float e = __expf(2.0f * x);
    return 1.0f - 2.0f / (e + 1.0f);
}

// ---------------- one-time prep kernels ----------------
__global__ void k_cvt(const float* __restrict__ src, _Float16* __restrict__ dst, int n) {
    int i = blockIdx.x * blockDim.x + threadIdx.x;
    if (i < n) dst[i] = (_Float16)src[i];
}

__global__ void k_bias_combine(const float* __restrict__ a, const float* __restrict__ b,
                               float* __restrict__ dst, int n) {
    int i = blockIdx.x * blockDim.x + threadIdx.x;
    if (i < n) dst[i] = a[i] + b[i];
}

// Wd[r,k] = dWhh[r,k] + sum_o dWih[r,o] * fcW[o,k]   (fp32 math, fp16 out)
// grid 256 blocks x 256 thr; block handles 8 rows r.
__global__ __launch_bounds__(256) void k_wd(
    const float* __restrict__ dWhh, const float* __restrict__ dWih,
    const float* __restrict__ fcW, _Float16* __restrict__ Wd)
{
    __shared__ float sA[8][256];
    const int tid = threadIdx.x;
    const int r0 = blockIdx.x * 8;
    {
        int linear = tid * 8;
        int row = linear >> 8, col = linear & 255;
        const float4* p = (const float4*)(dWih + (size_t)(r0 + row) * 256 + col);
        float4 v0 = p[0], v1 = p[1];
        *(float4*)&sA[row][col]     = v0;
        *(float4*)&sA[row][col + 4] = v1;
    }
    __syncthreads();
    float acc[8][2] = {};
    const int k = tid;
    for (int i = 0; i < 256; ++i) {
        float w0 = fcW[(size_t)i * 512 + k];
        float w1 = fcW[(size_t)i * 512 + k + 256];
        #pragma unroll
        for (int rr = 0; rr < 8; ++rr) {
            float a = sA[rr][i];
            acc[rr][0] += a * w0;
            acc[rr][1] += a * w1;
        }
    }
    #pragma unroll
    for (int rr = 0; rr < 8; ++rr) {
        size_t base = (size_t)(r0 + rr) * 512;
        Wd[base + k]       = (_Float16)(dWhh[base + k]       + acc[rr][0]);
        Wd[base + k + 256] = (_Float16)(dWhh[base + k + 256] + acc[rr][1]);
    }
}

// bd[r] = db[r] + sum_o dWih[r,o] * fcb[o]
__global__ __launch_bounds__(256) void k_bd(
    const float* __restrict__ dWih, const float* __restrict__ fcb,
    const float* __restrict__ db, float* __restrict__ bd)
{
    __shared__ float sf[256];
    const int tid = threadIdx.x;
    sf[tid] = fcb[tid];
    __syncthreads();
    int r = blockIdx.x * 256 + tid;
    float acc = db[r];
    const float* row = dWih + (size_t)r * 256;
    for (int o = 0; o < 256; o += 4) {
        float4 v = *(const float4*)(row + o);
        acc += v.x * sf[o] + v.y * sf[o + 1] + v.z * sf[o + 2] + v.w * sf[o + 3];
    }
    bd[r] = acc;
}

// ---------------- encoder x-projection (chunked big GEMM) ----------------
// xp frags: per (s_local, mb, cb): [4 waves][mf 4][nf 4][lane 64][4] halves
// gate-col mapping inside a 128-col block: col = wn*64 + nf*16 + lrow ->
//   gate = nf, jj = wn*16 + lrow, j = cb*32 + jj
__global__ __launch_bounds__(256) void k_xproj(
    const float* __restrict__ x, int s0,
    const _Float16* __restrict__ Wih,   // [2048][256] fp16
    const float* __restrict__ eb,       // [2048]
    _Float16* __restrict__ xp)
{
    __shared__ _Float16 Asm[128][PAD];
    __shared__ _Float16 Bsm[128][PAD];

    const int tid = threadIdx.x;
    const int bm = blockIdx.x;           // 0 .. CH*32-1
    const int cb = blockIdx.y;           // 0 .. 15
    const int s_local = bm >> 5;
    const int m0 = (bm & 31) * 128;      // batch row base
    const int j0 = cb * 32;
    const int s = s0 + s_local;

    const int wv = tid >> 6, lane = tid & 63, lrow = lane & 15, lk = (lane >> 4) * 8;
    const int wm = wv >> 1, wn = wv & 1;

    f32x4 acc[4][4] = {};

    const int srow = tid >> 3, skc = (tid & 7) * 8;

    for (int k0 = 0; k0 < I_SZ; k0 += 64) {
        __syncthreads();
        #pragma unroll
        for (int t = 0; t < 4; ++t) {
            int r = srow + t * 32;
            const float* p = x + ((size_t)(m0 + r) * S_SZ + s) * I_SZ + k0 + skc;
            float4 v0 = *(const float4*)p;
            float4 v1 = *(const float4*)(p + 4);
            half8 hv;
            hv[0] = (_Float16)v0.x; hv[1] = (_Float16)v0.y;
            hv[2] = (_Float16)v0.z; hv[3] = (_Float16)v0.w;
            hv[4] = (_Float16)v1.x; hv[5] = (_Float16)v1.y;
            hv[6] = (_Float16)v1.z; hv[7] = (_Float16)v1.w;
            *(half8*)&Asm[r][skc] = hv;
        }
        #pragma unroll
        for (int t = 0; t < 4; ++t) {
            int rr = srow + t * 32;
            int grow = ((rr >> 4) & 3) * H_SZ + j0 + ((rr >> 6) * 16) + (rr & 15);
            *(half8*)&Bsm[rr][skc] = *(const half8*)(Wih + (size_t)grow * I_SZ + k0 + skc);
        }
        __syncthreads();
        #pragma unroll
        for (int kc = 0; kc < 64; kc += 32) {
            half8 a[4], b[4];
            #pragma unroll
            for (int mf = 0; mf < 4; ++mf) a[mf] = *(const half8*)&Asm[wm * 64 + mf * 16 + lrow][kc + lk];
            #pragma unroll
            for (int nf = 0; nf < 4; ++nf) b[nf] = *(const half8*)&Bsm[wn * 64 + nf * 16 + lrow][kc + lk];
            #pragma unroll
            for (int mf = 0; mf < 4; ++mf)
                #pragma unroll
                for (int nf = 0; nf < 4; ++nf)
                    acc[mf][nf] = __builtin_amdgcn_mfma_f32_16x16x32_f16(a[mf], b[nf], acc[mf][nf], 0, 0, 0);
        }
    }

    float bj[4];
    #pragma unroll
    for (int nf = 0; nf < 4; ++nf) bj[nf] = eb[nf * H_SZ + j0 + wn * 16 + lrow];

    size_t base = (((size_t)(bm * 16 + cb) * 4 + wv) * 4096) + (size_t)lane * 4;
    #pragma unroll
    for (int mf = 0; mf < 4; ++mf)
        #pragma unroll
        for (int nf = 0; nf < 4; ++nf) {
            half4 hv;
            hv[0] = (_Float16)(acc[mf][nf][0] + bj[nf]);
            hv[1] = (_Float16)(acc[mf][nf][1] + bj[nf]);
            hv[2] = (_Float16)(acc[mf][nf][2] + bj[nf]);
            hv[3] = (_Float16)(acc[mf][nf][3] + bj[nf]);
            *(half4*)(xp + base + (mf * 4 + nf) * 256) = hv;
        }
}

// ---------------- encoder step 0: activation-only from xproj frags ----------------
__global__ __launch_bounds__(256) void k_first(
    const _Float16* __restrict__ xps, _Float16* __restrict__ hout, float* __restrict__ c)
{
    const int tid = threadIdx.x;
    const int wv = tid >> 6, lane = tid & 63, lrow = lane & 15;
    const int wm = wv >> 1, wn = wv & 1;
    const int m0 = blockIdx.x * 128, j0 = blockIdx.y * 32;

    size_t base = (((size_t)(blockIdx.x * 16 + blockIdx.y) * 4 + wv) * 4096) + (size_t)lane * 4;
    float g[4][4][4];
    #pragma unroll
    for (int mf = 0; mf < 4; ++mf)
        #pragma unroll
        for (int nf = 0; nf < 4; ++nf) {
            half4 hv = *(const half4*)(xps + base + (mf * 4 + nf) * 256);
            #pragma unroll
            for (int r = 0; r < 4; ++r) g[mf][nf][r] = (float)hv[r];
        }

    const int j = j0 + wn * 16 + lrow;
    #pragma unroll
    for (int mf = 0; mf < 4; ++mf)
        #pragma unroll
        for (int r = 0; r < 4; ++r) {
            int m = m0 + wm * 64 + mf * 16 + (lane >> 4) * 4 + r;
            float cn = sigm(g[mf][0][r]) * tanh_fast(g[mf][2][r]);   // c_old = 0
            float ov = sigm(g[mf][3][r]);
            size_t idx = (size_t)m * H_SZ + j;
            c[idx] = cn;
            hout[idx] = (_Float16)(ov * tanh_fast(cn));
        }
}

// ---------------- recurrent LSTM step (K = 512 only) ----------------
__global__ __launch_bounds__(256) void k_step(
    const _Float16* __restrict__ xps,  // frag pre-gates (bias folded in) or null
    const float* __restrict__ bias,    // or null when xps carries bias
    const _Float16* __restrict__ hin,  // [B][512] fp16
    const _Float16* __restrict__ W,    // [2048][512] fp16
    _Float16* __restrict__ hout,
    float* __restrict__ c)
{
    __shared__ _Float16 Asm[128][PAD];
    __shared__ _Float16 Bsm[128][PAD];

    const int tid = threadIdx.x;
    const int m0 = blockIdx.x * 128, j0 = blockIdx.y * 32;
    const int wv = tid >> 6, lane = tid & 63, lrow = lane & 15, lk = (lane >> 4) * 8;
    const int wm = wv >> 1, wn = wv & 1;

    f32x4 acc[4][4];
    if (xps) {
        size_t base = (((size_t)(blockIdx.x * 16 + blockIdx.y) * 4 + wv) * 4096) + (size_t)lane * 4;
        #pragma unroll
        for (int mf = 0; mf < 4; ++mf)
            #pragma unroll
            for (int nf = 0; nf < 4; ++nf) {
                half4 hv = *(const half4*)(xps + base + (mf * 4 + nf) * 256);
                f32x4 v = {(float)hv[0], (float)hv[1], (float)hv[2], (float)hv[3]};
                acc[mf][nf] = v;
            }
    } else {
        #pragma unroll
        for (int mf = 0; mf < 4; ++mf)
            #pragma unroll
            for (int nf = 0; nf < 4; ++nf) {
                f32x4 z = {0.f, 0.f, 0.f, 0.f};
                acc[mf][nf] = z;
            }
    }

    const int srow = tid >> 3, skc = (tid & 7) * 8;

    for (int k0 = 0; k0 < H_SZ; k0 += 64) {
        __syncthreads();
        #pragma unroll
        for (int t = 0; t < 4; ++t) {
            int r = srow + t * 32;
            *(half8*)&Asm[r][skc] = *(const half8*)(hin + (size_t)(m0 + r) * H_SZ + k0 + skc);
        }
        #pragma unroll
        for (int t = 0; t < 4; ++t) {
            int rr = srow + t * 32;
            int grow = ((rr >> 4) & 3) * H_SZ + j0 + ((rr >> 6) * 16) + (rr & 15);
            *(half8*)&Bsm[rr][skc] = *(const half8*)(W + (size_t)grow * H_SZ + k0 + skc);
        }
        __syncthreads();
        #pragma unroll
        for (int kc = 0; kc < 64; kc += 32) {
            half8 a[4], b[4];
            #pragma unroll
            for (int mf = 0; mf < 4; ++mf) a[mf] = *(const half8*)&Asm[wm * 64 + mf * 16 + lrow][kc + lk];
            #pragma unroll
            for (int nf = 0; nf < 4; ++nf) b[nf] = *(const half8*)&Bsm[wn * 64 + nf * 16 + lrow][kc + lk];
            #pragma unroll
            for (int mf = 0; mf < 4; ++mf)
                #pragma unroll
                for (int nf = 0; nf < 4; ++nf)
                    acc[mf][nf] = __builtin_amdgcn_mfma_f32_16x16x32_f16(a[mf], b[nf], acc[mf][nf], 0, 0, 0);
        }
    }

    float bj[4] = {0.f, 0.f, 0.f, 0.f};
    if (bias) {
        #pragma unroll
        for (int nf = 0; nf < 4; ++nf) bj[nf] = bias[nf * H_SZ + j0 + wn * 16 + lrow];
    }

    const int j = j0 + wn * 16 + lrow;
    #pragma unroll
    for (int mf = 0; mf < 4; ++mf)
        #pragma unroll
        for (int r = 0; r < 4; ++r) {
            int m = m0 + wm * 64 + mf * 16 + (lane >> 4) * 4 + r;
            float gi = acc[mf][0][r] + bj[0];
            float gf = acc[mf][1][r] + bj[1];
            float gg = acc[mf][2][r] + bj[2];
            float go = acc[mf][3][r] + bj[3];
            size_t idx = (size_t)m * H_SZ + j;
            float cn = sigm(gf) * c[idx] + sigm(gi) * tanh_fast(gg);
            c[idx] = cn;
            hout[idx] = (_Float16)(sigm(go) * tanh_fast(cn));
        }
}

// ---------------- batched final FC over all decoder h's ----------------
// grid (32 mb, 20 t, 2 nb); out[b][t][o] fp32
__global__ __launch_bounds__(256) void k_fc(
    const _Float16* __restrict__ hseq1,  // hseq slot 1 base: [T][B][512]
    const _Float16* __restrict__ W,      // fcW fp16 [256][512]
    const float* __restrict__ bias,      // [256]
    float* __restrict__ out)
{
    __shared__ _Float16 Asm[128][PAD];
    __shared__ _Float16 Bsm[128][PAD];

    const int tid = threadIdx.x;
    const int m0 = blockIdx.x * 128;
    const int t  = blockIdx.y;
    const int n0 = blockIdx.z * 128;
    const int wv = tid >> 6, lane = tid & 63, lrow = lane & 15, lk = (lane >> 4) * 8;
    const int wm = wv >> 1, wn = wv & 1;

    f32x4 acc[4][4] = {};

    const int srow = tid >> 3, skc = (tid & 7) * 8;
    const _Float16* A = hseq1 + (size_t)t * BH;

    for (int k0 = 0; k0 < H_SZ; k0 += 64) {
        __syncthreads();
        #pragma unroll
        for (int q = 0; q < 4; ++q) {
            int r = srow + q * 32;
            *(half8*)&Asm[r][skc] = *(const half8*)(A + (size_t)(m0 + r) * H_SZ + k0 + skc);
        }
        #pragma unroll
        for (int q = 0; q < 4; ++q) {
            int rr = srow + q * 32;
            *(half8*)&Bsm[rr][skc] = *(const half8*)(W + (size_t)(n0 + rr) * H_SZ + k0 + skc);
        }
        __syncthreads();
        #pragma unroll
        for (int kc = 0; kc < 64; kc += 32) {
            half8 a[4], b[4];
            #pragma unroll
            for (int mf = 0; mf < 4; ++mf) a[mf] = *(const half8*)&Asm[wm * 64 + mf * 16 + lrow][kc + lk];
            #pragma unroll
            for (int nf = 0; nf < 4; ++nf) b[nf] = *(const half8*)&Bsm[wn * 64 + nf * 16 + lrow][kc + lk];
            #pragma unroll
            for (int mf = 0; mf < 4; ++mf)
                #pragma unroll
                for (int nf = 0; nf < 4; ++nf)
                    acc[mf][nf] = __builtin_amdgcn_mfma_f32_16x16x32_f16(a[mf], b[nf], acc[mf][nf], 0, 0, 0);
        }
    }

    #pragma unroll
    for (int mf = 0; mf < 4; ++mf)
        #pragma unroll
        for (int nf = 0; nf < 4; ++nf) {
            int o = n0 + wn * 64 + nf * 16 + lrow;
            float bv = bias[o];
            #pragma unroll
            for (int r = 0; r < 4; ++r) {
                int m = m0 + wm * 64 + mf * 16 + (lane >> 4) * 4 + r;
                out[(size_t)m * (T_SZ * O_SZ) + (size_t)t * O_SZ + o] = acc[mf][nf][r] + bv;
            }
        }
}

extern "C" void kernel_launch(void* const* d_in, const int* in_sizes, int n_in,
                              void* d_out, int out_size, void* d_ws, size_t ws_size,
                              hipStream_t stream) {
    (void)in_sizes; (void)n_in; (void)out_size; (void)ws_size;

    const float* x    = (const float*)d_in[0];
    const float* eWih = (const float*)d_in[1];
    const float* eWhh = (const float*)d_in[2];
    const float* ebih = (const float*)d_in[3];
    const float* ebhh = (const float*)d_in[4];
    const float* dWih = (const float*)d_in[5];
    const float* dWhh = (const float*)d_in[6];
    const float* dbih = (const float*)d_in[7];
    const float* dbhh = (const float*)d_in[8];
    const float* fcW  = (const float*)d_in[9];
    const float* fcb  = (const float*)d_in[10];
    float* out = (float*)d_out;
    char* ws = (char*)d_ws;

    size_t off = 0;
    auto alloc = [&](size_t bytes) -> void* {
        void* p = ws + off;
        off += (bytes + 255) & ~(size_t)255;
        return p;
    };
    _Float16* eWih_h = (_Float16*)alloc((size_t)G4H * I_SZ * 2);
    _Float16* eWhh_h = (_Float16*)alloc((size_t)G4H * H_SZ * 2);
    _Float16* dWhh_h = (_Float16*)alloc((size_t)G4H * H_SZ * 2);
    _Float16* fcW_h  = (_Float16*)alloc((size_t)O_SZ * H_SZ * 2);
    _Float16* Wd     = (_Float16*)alloc((size_t)G4H * H_SZ * 2);
    float*    eb     = (float*)alloc(G4H * 4);
    float*    db     = (float*)alloc(G4H * 4);
    float*    bd     = (float*)alloc(G4H * 4);
    _Float16* h0     = (_Float16*)alloc(BH * 2);
    _Float16* h1     = (_Float16*)alloc(BH * 2);
    _Float16* hseq   = (_Float16*)alloc((size_t)(T_SZ + 1) * BH * 2);
    float*    cbuf   = (float*)alloc(BH * 4);
    _Float16* xp     = (_Float16*)alloc((size_t)CH * XP_SLICE * 2);

    const int nWih = G4H * I_SZ;
    const int nWhh = G4H * H_SZ;
    const int nFc  = O_SZ * H_SZ;

    k_cvt<<<(nWih + 255) / 256, 256, 0, stream>>>(eWih, eWih_h, nWih);
    k_cvt<<<(nWhh + 255) / 256, 256, 0, stream>>>(eWhh, eWhh_h, nWhh);
    k_cvt<<<(nWhh + 255) / 256, 256, 0, stream>>>(dWhh, dWhh_h, nWhh);
    k_cvt<<<(nFc  + 255) / 256, 256, 0, stream>>>(fcW, fcW_h, nFc);
    k_bias_combine<<<8, 256, 0, stream>>>(ebih, ebhh, eb, G4H);
    k_bias_combine<<<8, 256, 0, stream>>>(dbih, dbhh, db, G4H);
    k_wd<<<256, 256, 0, stream>>>(dWhh, dWih, fcW, Wd);
    k_bd<<<8, 256, 0, stream>>>(dWih, fcb, db, bd);

    dim3 gs(B_SZ / 128, G4H / 128);   // (32, 16)
    dim3 blk(256);

    _Float16* hprev = h0;
    for (int chunk = 0; chunk < S_SZ / CH; ++chunk) {
        int s0 = chunk * CH;
        k_xproj<<<dim3(CH * 32, 16), blk, 0, stream>>>(x, s0, eWih_h, eb, xp);
        for (int s = s0; s < s0 + CH; ++s) {
            const _Float16* xps = xp + (size_t)(s - s0) * XP_SLICE;
            if (s == 0) {
                k_first<<<gs, blk, 0, stream>>>(xps, h0, cbuf);
                hprev = h0;
            } else {
                _Float16* hout = (s == S_SZ - 1) ? hseq : ((s & 1) ? h1 : h0);
                k_step<<<gs, blk, 0, stream>>>(xps, nullptr, hprev, eWhh_h, hout, cbuf);
                hprev = hout;
            }
        }
    }

    for (int t = 0; t < T_SZ; ++t) {
        const _Float16* hin = hseq + (size_t)t * BH;
        _Float16* hout = hseq + (size_t)(t + 1) * BH;
        k_step<<<gs, blk, 0, stream>>>(nullptr, (t == 0) ? db : bd, hin,
                                       (t == 0) ? dWhh_h : Wd, hout, cbuf);
    }

    k_fc<<<dim3(B_SZ / 128, T_SZ, O_SZ / 128), blk, 0, stream>>>(hseq + BH, fcW_h, fcb, out);
}

// Round 3
// 1716.105 us; speedup vs baseline: 1.2363x; 1.2363x over previous
//
#include <hip/hip_runtime.h>

#define I_SZ 256
#define H_SZ 512
#define O_SZ 256
#define B_SZ 4096
#define S_SZ 50
#define T_SZ 20
#define G4H  2048
#define BH   ((size_t)B_SZ * H_SZ)

#define PAD 72   // only used by k_fc (validated round-2 kernel)

typedef _Float16 half8 __attribute__((ext_vector_type(8)));
typedef _Float16 half4 __attribute__((ext_vector_type(4)));
typedef float f32x4 __attribute__((ext_vector_type(4)));

__device__ __forceinline__ float sigm(float x) {
    return 1.0f / (1.0f + __expf(-x));
}
__device__ __forceinline__ float tanh_fast(float x) {
    float e = __expf(2.0f * x);
    return 1.0f - 2.0f / (e + 1.0f);
}

// async global->LDS, 16B per lane, linear LDS dest (wave-uniform base + lane*16)
#define GLDS(gp, lp) __builtin_amdgcn_global_load_lds(                      \
    (const __attribute__((address_space(1))) void*)(gp),                    \
    (__attribute__((address_space(3))) void*)(lp), 16, 0, 0)

// ---------------- one-time prep kernels ----------------
__global__ void k_cvt(const float* __restrict__ src, _Float16* __restrict__ dst, int n) {
    int i = blockIdx.x * blockDim.x + threadIdx.x;
    if (i < n) dst[i] = (_Float16)src[i];
}

__global__ void k_bias_combine(const float* __restrict__ a, const float* __restrict__ b,
                               float* __restrict__ dst, int n) {
    int i = blockIdx.x * blockDim.x + threadIdx.x;
    if (i < n) dst[i] = a[i] + b[i];
}

// x [B][S][I] fp32 -> xT [S][B][I] fp16  (8 elems/thread, coalesced read)
__global__ __launch_bounds__(256) void k_cvt_x(const float* __restrict__ x,
                                               _Float16* __restrict__ xT) {
    size_t idx = ((size_t)blockIdx.x * 256 + threadIdx.x) * 8;
    int i = (int)(idx & 255);
    int s = (int)((idx >> 8) % S_SZ);
    size_t b = idx / (256 * S_SZ);
    float4 v0 = *(const float4*)(x + idx);
    float4 v1 = *(const float4*)(x + idx + 4);
    half8 hv;
    hv[0] = (_Float16)v0.x; hv[1] = (_Float16)v0.y;
    hv[2] = (_Float16)v0.z; hv[3] = (_Float16)v0.w;
    hv[4] = (_Float16)v1.x; hv[5] = (_Float16)v1.y;
    hv[6] = (_Float16)v1.z; hv[7] = (_Float16)v1.w;
    *(half8*)(xT + (((size_t)s * B_SZ + b) * I_SZ + i)) = hv;
}

// Wenc[r][0:256]=eWih[r], [256:768]=eWhh[r]  (fp16)
__global__ void k_wenc(const float* __restrict__ eWih, const float* __restrict__ eWhh,
                       _Float16* __restrict__ Wenc) {
    int idx = blockIdx.x * blockDim.x + threadIdx.x;   // 2048*768
    int r = idx / 768, col = idx % 768;
    float v = (col < 256) ? eWih[(size_t)r * 256 + col] : eWhh[(size_t)r * 512 + col - 256];
    Wenc[idx] = (_Float16)v;
}

// Wd[r,k] = dWhh[r,k] + sum_o dWih[r,o] * fcW[o,k]   (fp32 math, fp16 out)
__global__ __launch_bounds__(256) void k_wd(
    const float* __restrict__ dWhh, const float* __restrict__ dWih,
    const float* __restrict__ fcW, _Float16* __restrict__ Wd)
{
    __shared__ float sA[8][256];
    const int tid = threadIdx.x;
    const int r0 = blockIdx.x * 8;
    {
        int linear = tid * 8;
        int row = linear >> 8, col = linear & 255;
        const float4* p = (const float4*)(dWih + (size_t)(r0 + row) * 256 + col);
        float4 v0 = p[0], v1 = p[1];
        *(float4*)&sA[row][col]     = v0;
        *(float4*)&sA[row][col + 4] = v1;
    }
    __syncthreads();
    float acc[8][2] = {};
    const int k = tid;
    for (int i = 0; i < 256; ++i) {
        float w0 = fcW[(size_t)i * 512 + k];
        float w1 = fcW[(size_t)i * 512 + k + 256];
        #pragma unroll
        for (int rr = 0; rr < 8; ++rr) {
            float a = sA[rr][i];
            acc[rr][0] += a * w0;
            acc[rr][1] += a * w1;
        }
    }
    #pragma unroll
    for (int rr = 0; rr < 8; ++rr) {
        size_t base = (size_t)(r0 + rr) * 512;
        Wd[base + k]       = (_Float16)(dWhh[base + k]       + acc[rr][0]);
        Wd[base + k + 256] = (_Float16)(dWhh[base + k + 256] + acc[rr][1]);
    }
}

// bd[r] = db[r] + sum_o dWih[r,o] * fcb[o]
__global__ __launch_bounds__(256) void k_bd(
    const float* __restrict__ dWih, const float* __restrict__ fcb,
    const float* __restrict__ db, float* __restrict__ bd)
{
    __shared__ float sf[256];
    const int tid = threadIdx.x;
    sf[tid] = fcb[tid];
    __syncthreads();
    int r = blockIdx.x * 256 + tid;
    float acc = db[r];
    const float* row = dWih + (size_t)r * 256;
    for (int o = 0; o < 256; o += 4) {
        float4 v = *(const float4*)(row + o);
        acc += v.x * sf[o] + v.y * sf[o + 1] + v.z * sf[o + 2] + v.w * sf[o + 3];
    }
    bd[r] = acc;
}

// ---------------- fused recurrent LSTM step ----------------
// gates = [x_t | h] @ W^T + bias; cell update fused.
// Block 256 thr (4 waves, 2x2 split), tile 128 batch x 128 gate-cols (4 gates x 32 j).
// Staging: global_load_lds width16, linear LDS, XOR-swizzled source + reads (T2/rule21).
// 2-phase double-buffered pipeline (stage(next) before compute(cur), 1 barrier/tile).
__global__ __launch_bounds__(256) void k_step(
    const _Float16* __restrict__ xsrc,  // xT slab [B][256] or null
    const _Float16* __restrict__ hin,   // [B][512] or null (first)
    const _Float16* __restrict__ W,     // [2048][wstride] fp16
    int wstride, int nx, int niter,     // nx = x-iters (K1/64), niter total k0 iters
    const float* __restrict__ bias,     // [2048]
    _Float16* __restrict__ hout,        // [B][512]
    float* __restrict__ c,              // [B][512] fp32
    int first)                          // 1: don't read c
{
    __shared__ _Float16 lds[2][2][128 * 64];   // [buf][A/B][row*64+col] 64 KB

    const int tid = threadIdx.x;
    const int m0 = blockIdx.x * 128, j0 = blockIdx.y * 32;
    const int wv = tid >> 6, lane = tid & 63, lrow = lane & 15, lk8 = (lane >> 4) * 8;
    const int wm = wv >> 1, wn = wv & 1;

    // ---- staging geometry (per thread; 4 issues each for A and B) ----
    const int colb  = (lane & 7) * 16;                    // byte col in 128-B row
    const int scolh = (colb ^ (((lane >> 3) & 7) << 4)) >> 1;  // swizzled, in halves
    int rowq[4], growq[4];
    #pragma unroll
    for (int q = 0; q < 4; ++q) {
        int r = q * 32 + wv * 8 + (lane >> 3);
        rowq[q] = r;
        growq[q] = ((r >> 4) & 3) * H_SZ + j0 + (r >> 6) * 16 + (r & 15);
    }

    auto stage = [&](int buf, int it) {
        const int koffW = it * 64;
        const _Float16* Ab; int astr, koffA;
        if (it < nx) { Ab = xsrc; astr = I_SZ; koffA = it * 64; }
        else         { Ab = hin;  astr = H_SZ; koffA = (it - nx) * 64; }
        #pragma unroll
        for (int q = 0; q < 4; ++q) {
            const _Float16* ga = Ab + (size_t)(m0 + rowq[q]) * astr + koffA + scolh;
            GLDS(ga, &lds[buf][0][(q * 256 + wv * 64) * 8]);
        }
        #pragma unroll
        for (int q = 0; q < 4; ++q) {
            const _Float16* gb = W + (size_t)growq[q] * wstride + koffW + scolh;
            GLDS(gb, &lds[buf][1][(q * 256 + wv * 64) * 8]);
        }
    };

    f32x4 acc[4][4] = {};

    auto compute = [&](int buf) {
        #pragma unroll
        for (int kc = 0; kc < 2; ++kc) {
            const int cb = (kc * 32 + lk8) * 2;
            const int sc = (cb ^ ((lrow & 7) << 4)) >> 1;   // halves
            half8 a[4], b[4];
            #pragma unroll
            for (int mf = 0; mf < 4; ++mf) {
                int ar = wm * 64 + mf * 16 + lrow;
                a[mf] = *(const half8*)&lds[buf][0][ar * 64 + sc];
            }
            #pragma unroll
            for (int nf = 0; nf < 4; ++nf) {
                int br = wn * 64 + nf * 16 + lrow;
                b[nf] = *(const half8*)&lds[buf][1][br * 64 + sc];
            }
            #pragma unroll
            for (int mf = 0; mf < 4; ++mf)
                #pragma unroll
                for (int nf = 0; nf < 4; ++nf)
                    acc[mf][nf] = __builtin_amdgcn_mfma_f32_16x16x32_f16(a[mf], b[nf], acc[mf][nf], 0, 0, 0);
        }
    };

    stage(0, 0);
    __syncthreads();
    int buf = 0;
    for (int it = 0; it < niter; ++it) {
        if (it + 1 < niter) stage(buf ^ 1, it + 1);
        compute(buf);
        __syncthreads();
        buf ^= 1;
    }

    // ---- epilogue: bias + activations + cell update ----
    float bj[4];
    #pragma unroll
    for (int nf = 0; nf < 4; ++nf) bj[nf] = bias[nf * H_SZ + j0 + wn * 16 + lrow];

    const int j = j0 + wn * 16 + lrow;
    #pragma unroll
    for (int mf = 0; mf < 4; ++mf)
        #pragma unroll
        for (int r = 0; r < 4; ++r) {
            int m = m0 + wm * 64 + mf * 16 + (lane >> 4) * 4 + r;
            float gi = acc[mf][0][r] + bj[0];
            float gf = acc[mf][1][r] + bj[1];
            float gg = acc[mf][2][r] + bj[2];
            float go = acc[mf][3][r] + bj[3];
            size_t idx = (size_t)m * H_SZ + j;
            float cold = first ? 0.0f : c[idx];
            float cn = sigm(gf) * cold + sigm(gi) * tanh_fast(gg);
            c[idx] = cn;
            hout[idx] = (_Float16)(sigm(go) * tanh_fast(cn));
        }
}

// ---------------- batched final FC over all decoder h's ----------------
__global__ __launch_bounds__(256) void k_fc(
    const _Float16* __restrict__ hseq1,  // [T][B][512]
    const _Float16* __restrict__ W,      // fcW fp16 [256][512]
    const float* __restrict__ bias,      // [256]
    float* __restrict__ out)
{
    __shared__ _Float16 Asm[128][PAD];
    __shared__ _Float16 Bsm[128][PAD];

    const int tid = threadIdx.x;
    const int m0 = blockIdx.x * 128;
    const int t  = blockIdx.y;
    const int n0 = blockIdx.z * 128;
    const int wv = tid >> 6, lane = tid & 63, lrow = lane & 15, lk = (lane >> 4) * 8;
    const int wm = wv >> 1, wn = wv & 1;

    f32x4 acc[4][4] = {};

    const int srow = tid >> 3, skc = (tid & 7) * 8;
    const _Float16* A = hseq1 + (size_t)t * BH;

    for (int k0 = 0; k0 < H_SZ; k0 += 64) {
        __syncthreads();
        #pragma unroll
        for (int q = 0; q < 4; ++q) {
            int r = srow + q * 32;
            *(half8*)&Asm[r][skc] = *(const half8*)(A + (size_t)(m0 + r) * H_SZ + k0 + skc);
        }
        #pragma unroll
        for (int q = 0; q < 4; ++q) {
            int rr = srow + q * 32;
            *(half8*)&Bsm[rr][skc] = *(const half8*)(W + (size_t)(n0 + rr) * H_SZ + k0 + skc);
        }
        __syncthreads();
        #pragma unroll
        for (int kc = 0; kc < 64; kc += 32) {
            half8 a[4], b[4];
            #pragma unroll
            for (int mf = 0; mf < 4; ++mf) a[mf] = *(const half8*)&Asm[wm * 64 + mf * 16 + lrow][kc + lk];
            #pragma unroll
            for (int nf = 0; nf < 4; ++nf) b[nf] = *(const half8*)&Bsm[wn * 64 + nf * 16 + lrow][kc + lk];
            #pragma unroll
            for (int mf = 0; mf < 4; ++mf)
                #pragma unroll
                for (int nf = 0; nf < 4; ++nf)
                    acc[mf][nf] = __builtin_amdgcn_mfma_f32_16x16x32_f16(a[mf], b[nf], acc[mf][nf], 0, 0, 0);
        }
    }

    #pragma unroll
    for (int mf = 0; mf < 4; ++mf)
        #pragma unroll
        for (int nf = 0; nf < 4; ++nf) {
            int o = n0 + wn * 64 + nf * 16 + lrow;
            float bv = bias[o];
            #pragma unroll
            for (int r = 0; r < 4; ++r) {
                int m = m0 + wm * 64 + mf * 16 + (lane >> 4) * 4 + r;
                out[(size_t)m * (T_SZ * O_SZ) + (size_t)t * O_SZ + o] = acc[mf][nf][r] + bv;
            }
        }
}

extern "C" void kernel_launch(void* const* d_in, const int* in_sizes, int n_in,
                              void* d_out, int out_size, void* d_ws, size_t ws_size,
                              hipStream_t stream) {
    (void)in_sizes; (void)n_in; (void)out_size; (void)ws_size;

    const float* x    = (const float*)d_in[0];
    const float* eWih = (const float*)d_in[1];
    const float* eWhh = (const float*)d_in[2];
    const float* ebih = (const float*)d_in[3];
    const float* ebhh = (const float*)d_in[4];
    const float* dWih = (const float*)d_in[5];
    const float* dWhh = (const float*)d_in[6];
    const float* dbih = (const float*)d_in[7];
    const float* dbhh = (const float*)d_in[8];
    const float* fcW  = (const float*)d_in[9];
    const float* fcb  = (const float*)d_in[10];
    float* out = (float*)d_out;
    char* ws = (char*)d_ws;

    size_t off = 0;
    auto alloc = [&](size_t bytes) -> void* {
        void* p = ws + off;
        off += (bytes + 255) & ~(size_t)255;
        return p;
    };
    _Float16* xT     = (_Float16*)alloc((size_t)S_SZ * B_SZ * I_SZ * 2);
    _Float16* Wenc   = (_Float16*)alloc((size_t)G4H * (I_SZ + H_SZ) * 2);
    _Float16* dWhh_h = (_Float16*)alloc((size_t)G4H * H_SZ * 2);
    _Float16* Wd     = (_Float16*)alloc((size_t)G4H * H_SZ * 2);
    _Float16* fcW_h  = (_Float16*)alloc((size_t)O_SZ * H_SZ * 2);
    float*    eb     = (float*)alloc(G4H * 4);
    float*    db     = (float*)alloc(G4H * 4);
    float*    bd     = (float*)alloc(G4H * 4);
    _Float16* h0     = (_Float16*)alloc(BH * 2);
    _Float16* h1     = (_Float16*)alloc(BH * 2);
    _Float16* hseq   = (_Float16*)alloc((size_t)(T_SZ + 1) * BH * 2);
    float*    cbuf   = (float*)alloc(BH * 4);

    const int nWhh = G4H * H_SZ;
    const int nFc  = O_SZ * H_SZ;
    const size_t nX = (size_t)B_SZ * S_SZ * I_SZ;

    k_cvt_x<<<(int)(nX / 8 / 256), 256, 0, stream>>>(x, xT);
    k_wenc<<<(G4H * 768) / 256, 256, 0, stream>>>(eWih, eWhh, Wenc);
    k_cvt<<<(nWhh + 255) / 256, 256, 0, stream>>>(dWhh, dWhh_h, nWhh);
    k_cvt<<<(nFc + 255) / 256, 256, 0, stream>>>(fcW, fcW_h, nFc);
    k_bias_combine<<<8, 256, 0, stream>>>(ebih, ebhh, eb, G4H);
    k_bias_combine<<<8, 256, 0, stream>>>(dbih, dbhh, db, G4H);
    k_wd<<<256, 256, 0, stream>>>(dWhh, dWih, fcW, Wd);
    k_bd<<<8, 256, 0, stream>>>(dWih, fcb, db, bd);

    dim3 gs(B_SZ / 128, G4H / 128);   // (32, 16)
    dim3 blk(256);

    // ---- encoder ----
    _Float16* hprev = nullptr;
    for (int s = 0; s < S_SZ; ++s) {
        const _Float16* xs = xT + (size_t)s * B_SZ * I_SZ;
        _Float16* houtp = (s == S_SZ - 1) ? hseq : ((s & 1) ? h1 : h0);
        if (s == 0) {
            k_step<<<gs, blk, 0, stream>>>(xs, nullptr, Wenc, 768, 4, 4, eb, houtp, cbuf, 1);
        } else {
            k_step<<<gs, blk, 0, stream>>>(xs, hprev, Wenc, 768, 4, 12, eb, houtp, cbuf, 0);
        }
        hprev = houtp;
    }

    // ---- decoder (fold: out_{t-1} feedback absorbed into Wd/bd) ----
    for (int t = 0; t < T_SZ; ++t) {
        const _Float16* hin = hseq + (size_t)t * BH;
        _Float16* houtp = hseq + (size_t)(t + 1) * BH;
        k_step<<<gs, blk, 0, stream>>>(nullptr, hin, (t == 0) ? dWhh_h : Wd, 512, 0, 8,
                                       (t == 0) ? db : bd, houtp, cbuf, 0);
    }

    k_fc<<<dim3(B_SZ / 128, T_SZ, O_SZ / 128), blk, 0, stream>>>(hseq + BH, fcW_h, fcb, out);
}